// Round 6
// baseline (130.949 us; speedup 1.0000x reference)
//
#include <hip/hip_runtime.h>

// Node record layout (stride 16 floats = 64B):
//   [0..8]   Frame[k][j] (row-major)
//   [9..11]  pF[j] = sum_k pos[k]*Frame[k][j]
//   [12..14] pos[0..2]
//   [15]     sA = sum_{h,j} silu(A[h][j]) * Wa[waOff + h*3 + j]
#define REC_STRIDE 16

#define KPB 128        // keys per bin
#define KPB_SHIFT 7
#define EPB 4096       // edges per block (hist + fused score/scatter)
#define MAXBINS 512

#define SEG_PAD 16     // fallback path
#define NREP 2

__device__ __forceinline__ float silu_f(float x)
{
    return x * __builtin_amdgcn_rcpf(1.f + __expf(-x));
}

__global__ void pre_node(const float* __restrict__ vec, const float* __restrict__ frame,
                         const float* __restrict__ pos, const float* __restrict__ W,
                         const float* __restrict__ Wa, int waOff,
                         float* __restrict__ out, int n)
{
    int i = blockIdx.x * blockDim.x + threadIdx.x;
    if (i >= n) return;

    float w[16][3];
#pragma unroll
    for (int d = 0; d < 16; ++d) {
        w[d][0] = W[d * 3 + 0];
        w[d][1] = W[d * 3 + 1];
        w[d][2] = W[d * 3 + 2];
    }
    float vt[3][3] = {{0.f}};  // [k][h]
    const float* vp = vec + (size_t)i * 48;
#pragma unroll
    for (int d = 0; d < 16; ++d) {
        float r0 = vp[d * 3 + 0], r1 = vp[d * 3 + 1], r2 = vp[d * 3 + 2];
#pragma unroll
        for (int h = 0; h < 3; ++h) {
            vt[0][h] += r0 * w[d][h];
            vt[1][h] += r1 * w[d][h];
            vt[2][h] += r2 * w[d][h];
        }
    }
    float F[9];
#pragma unroll
    for (int j = 0; j < 9; ++j) F[j] = frame[(size_t)i * 9 + j];
    float p0 = pos[(size_t)i * 3 + 0];
    float p1 = pos[(size_t)i * 3 + 1];
    float p2 = pos[(size_t)i * 3 + 2];

    float sA = 0.f;
#pragma unroll
    for (int h = 0; h < 3; ++h)
#pragma unroll
        for (int j = 0; j < 3; ++j) {
            float a = vt[0][h] * F[0 + j] + vt[1][h] * F[3 + j] + vt[2][h] * F[6 + j];
            sA += silu_f(a) * Wa[waOff + h * 3 + j];
        }

    float o[16];
#pragma unroll
    for (int j = 0; j < 9; ++j) o[j] = F[j];
#pragma unroll
    for (int j = 0; j < 3; ++j) o[9 + j] = p0 * F[j] + p1 * F[3 + j] + p2 * F[6 + j];
    o[12] = p0; o[13] = p1; o[14] = p2;
    o[15] = sA;

    float4* op = (float4*)(out + (size_t)i * REC_STRIDE);
#pragma unroll
    for (int q = 0; q < 4; ++q) op[q] = ((const float4*)o)[q];
}

// hist, transposed: hist_t[bin * nblk + blk] = count of edges in block blk with key-bin bin
__global__ void hist_t_kernel(const int* __restrict__ inc, int E, int nbins, int nblk,
                              unsigned* __restrict__ hist_t)
{
    __shared__ unsigned cnt[MAXBINS];
    for (int t = threadIdx.x; t < nbins; t += blockDim.x) cnt[t] = 0;
    __syncthreads();
    int base = blockIdx.x * EPB;
    int end = min(base + EPB, E);
    for (int e = base + (int)threadIdx.x; e < end; e += blockDim.x) {
        int fi = __builtin_nontemporal_load(inc + e);
        atomicAdd(&cnt[fi >> KPB_SHIFT], 1u);
    }
    __syncthreads();
    for (int t = threadIdx.x; t < nbins; t += blockDim.x)
        hist_t[(size_t)t * nblk + blockIdx.x] = cnt[t];
}

__device__ __forceinline__ unsigned wave_incl_scan(unsigned v, int lane)
{
    int x = (int)v;
#pragma unroll
    for (int d = 1; d < 64; d <<= 1) {
        int t = __shfl_up(x, d, 64);
        if (lane >= d) x += t;
    }
    return (unsigned)x;
}

// one wave per bin: convert hist_t row to within-row exclusive prefix, emit row total
__global__ void scan_rows(unsigned* __restrict__ hist_t, unsigned* __restrict__ binTotal,
                          int nbins, int nblk)
{
    int wid = (int)((blockIdx.x * blockDim.x + threadIdx.x) >> 6);
    int lane = (int)(threadIdx.x & 63);
    if (wid >= nbins) return;
    unsigned* row = hist_t + (size_t)wid * nblk;
    unsigned carry = 0;
    for (int c0 = 0; c0 < nblk; c0 += 64) {
        int i = c0 + lane;
        unsigned v = (i < nblk) ? row[i] : 0u;
        unsigned incl = wave_incl_scan(v, lane);
        if (i < nblk) row[i] = (incl - v) + carry;
        carry += (unsigned)__shfl((int)incl, 63, 64);
    }
    if (lane == 0) binTotal[wid] = carry;
}

// single wave: exclusive scan of binTotal -> binStart[0..nbins]
__global__ void scan_bins(const unsigned* __restrict__ binTotal, unsigned* __restrict__ binStart,
                          int nbins)
{
    int lane = (int)(threadIdx.x & 63);
    unsigned carry = 0;
    for (int c0 = 0; c0 < nbins; c0 += 64) {
        int i = c0 + lane;
        unsigned v = (i < nbins) ? binTotal[i] : 0u;
        unsigned incl = wave_incl_scan(v, lane);
        if (i < nbins) binStart[i] = (incl - v) + carry;
        carry += (unsigned)__shfl((int)incl, 63, 64);
    }
    if (lane == 0) binStart[nbins] = carry;
}

// fused: compute ex, write out[e], and scatter packed (ex | fi&127) into bin-grouped pairs
__global__ void edge_score_fused(const int* __restrict__ inc,
                                 const float* __restrict__ fromRec, const float* __restrict__ toRec,
                                 const float* __restrict__ Wa,
                                 const unsigned* __restrict__ hist_t,  // within-row exclusive prefixes
                                 const unsigned* __restrict__ binStart,
                                 float* __restrict__ ex_out, unsigned* __restrict__ pairs,
                                 int E, int nbins, int nblk)
{
    __shared__ unsigned cur[MAXBINS];
    for (int t = threadIdx.x; t < nbins; t += blockDim.x)
        cur[t] = hist_t[(size_t)t * nblk + blockIdx.x] + binStart[t];
    __syncthreads();

    float wa9 = Wa[9], wa10 = Wa[10], wa11 = Wa[11];
    float wa21 = Wa[21], wa22 = Wa[22], wa23 = Wa[23];

    int base = blockIdx.x * EPB;
    int end = min(base + EPB, E);
    for (int e = base + (int)threadIdx.x; e < end; e += blockDim.x) {
        int fi = __builtin_nontemporal_load(inc + e);
        int ti = __builtin_nontemporal_load(inc + E + e);

        float fr[16], tr[16];
        const float4* fp4 = (const float4*)(fromRec + (size_t)fi * REC_STRIDE);
        const float4* tp4 = (const float4*)(toRec + (size_t)ti * REC_STRIDE);
#pragma unroll
        for (int q = 0; q < 4; ++q) ((float4*)fr)[q] = fp4[q];
#pragma unroll
        for (int q = 0; q < 4; ++q) ((float4*)tr)[q] = tp4[q];

        float raw = fr[15] + tr[15];
#pragma unroll
        for (int j = 0; j < 3; ++j) {
            float fd = tr[12] * fr[j] + tr[13] * fr[3 + j] + tr[14] * fr[6 + j] - fr[9 + j];
            float td = fr[12] * tr[j] + fr[13] * tr[3 + j] + fr[14] * tr[6 + j] - tr[9 + j];
            float waf = (j == 0) ? wa9 : (j == 1) ? wa10 : wa11;
            float wat = (j == 0) ? wa21 : (j == 1) ? wa22 : wa23;
            raw += silu_f(fd) * waf + silu_f(td) * wat;
        }

        float ex = __expf(raw);  // shift-invariant softmax, |raw| << 80
        __builtin_nontemporal_store(ex, ex_out + e);

        unsigned slot = atomicAdd(&cur[fi >> KPB_SHIFT], 1u);
        // steal low 7 mantissa bits for the in-bin key (rel err <= 2^-17)
        unsigned w = (__float_as_uint(ex) & ~127u) | (unsigned)(fi & (KPB - 1));
        __builtin_nontemporal_store(w, pairs + slot);
    }
}

__global__ void binsum_kernel(const unsigned* __restrict__ pairs,
                              const unsigned* __restrict__ binStart,
                              float* __restrict__ segsum, int NF)
{
    __shared__ float acc[KPB];
    int b = blockIdx.x;
    if (threadIdx.x < KPB) acc[threadIdx.x] = 0.f;
    __syncthreads();
    unsigned s0 = binStart[b], s1 = binStart[b + 1];
    for (unsigned s = s0 + threadIdx.x; s < s1; s += blockDim.x) {
        unsigned w = pairs[s];
        atomicAdd(&acc[w & (KPB - 1)], __uint_as_float(w & ~127u));
    }
    __syncthreads();
    int k = (b << KPB_SHIFT) + (int)threadIdx.x;
    if (threadIdx.x < KPB && k < NF) segsum[k] = acc[threadIdx.x];
}

__global__ void edge_norm(const int* __restrict__ inc, const float* __restrict__ segsum,
                          float* __restrict__ out, int E)
{
    int e = blockIdx.x * blockDim.x + threadIdx.x;
    if (e >= E) return;
    int fi = __builtin_nontemporal_load(inc + e);
    float ex = out[e];
    __builtin_nontemporal_store(ex * __builtin_amdgcn_rcpf(segsum[fi]), out + e);
}

// -------- fallback: padded-replicated atomic edge_score (validated round 5) ----------
__global__ void edge_score_pad(const int* __restrict__ inc,
                               const float* __restrict__ fromRec, const float* __restrict__ toRec,
                               const float* __restrict__ Wa,
                               float* __restrict__ ex_out, float* __restrict__ segsumP, int E)
{
    int e = blockIdx.x * blockDim.x + threadIdx.x;
    if (e >= E) return;
    int fi = __builtin_nontemporal_load(inc + e);
    int ti = __builtin_nontemporal_load(inc + E + e);
    float fr[16], tr[16];
    const float4* fp4 = (const float4*)(fromRec + (size_t)fi * REC_STRIDE);
    const float4* tp4 = (const float4*)(toRec + (size_t)ti * REC_STRIDE);
#pragma unroll
    for (int q = 0; q < 4; ++q) ((float4*)fr)[q] = fp4[q];
#pragma unroll
    for (int q = 0; q < 4; ++q) ((float4*)tr)[q] = tp4[q];
    float raw = fr[15] + tr[15];
#pragma unroll
    for (int j = 0; j < 3; ++j) {
        float fd = tr[12] * fr[j] + tr[13] * fr[3 + j] + tr[14] * fr[6 + j] - fr[9 + j];
        float td = fr[12] * tr[j] + fr[13] * tr[3 + j] + fr[14] * tr[6 + j] - tr[9 + j];
        raw += silu_f(fd) * Wa[9 + j] + silu_f(td) * Wa[21 + j];
    }
    float ex = __expf(raw);
    __builtin_nontemporal_store(ex, ex_out + e);
    size_t slot = ((size_t)fi * NREP + (threadIdx.x & (NREP - 1))) * SEG_PAD;
    atomicAdd(&segsumP[slot], ex);
}

__global__ void seg_reduce(const float* __restrict__ segsumP, float* __restrict__ segsum, int NF)
{
    int k = blockIdx.x * blockDim.x + threadIdx.x;
    if (k >= NF) return;
    float s = 0.f;
#pragma unroll
    for (int r = 0; r < NREP; ++r) s += segsumP[((size_t)k * NREP + r) * SEG_PAD];
    segsum[k] = s;
}

extern "C" void kernel_launch(void* const* d_in, const int* in_sizes, int n_in,
                              void* d_out, int out_size, void* d_ws, size_t ws_size,
                              hipStream_t stream)
{
    const float* from_vec   = (const float*)d_in[0];
    const float* to_vec     = (const float*)d_in[1];
    const float* from_frame = (const float*)d_in[2];
    const float* to_frame   = (const float*)d_in[3];
    const float* from_pos   = (const float*)d_in[4];
    const float* to_pos     = (const float*)d_in[5];
    const float* W_from     = (const float*)d_in[6];
    const float* W_to       = (const float*)d_in[7];
    const float* W_attn     = (const float*)d_in[8];
    const int*   inc        = (const int*)d_in[9];

    const int NF = in_sizes[0] / 48;   // 50000
    const int NT = in_sizes[1] / 48;   // 100000
    const int E  = in_sizes[9] / 2;    // 1600000

    float* out = (float*)d_out;
    unsigned char* ws = (unsigned char*)d_ws;

    const int nbins = (NF + KPB - 1) >> KPB_SHIFT;        // 391
    const int nblk  = (E + EPB - 1) / EPB;                // 391

    auto align256 = [](size_t x) { return (x + 255) & ~(size_t)255; };

    size_t offFrom = 0;
    size_t offTo   = align256(offFrom + (size_t)NF * REC_STRIDE * 4);
    size_t offPair = align256(offTo   + (size_t)NT * REC_STRIDE * 4);
    size_t offSeg  = align256(offPair + (size_t)E * 4);
    size_t offHist = align256(offSeg  + (size_t)NF * 4);
    size_t offBT   = align256(offHist + (size_t)nbins * nblk * 4);
    size_t offBS   = align256(offBT   + (size_t)nbins * 4);
    size_t needFull = offBS + (size_t)(nbins + 1) * 4;

    const size_t recsz   = ((size_t)NF + NT) * REC_STRIDE * 4;
    const size_t padsz   = (size_t)NF * NREP * SEG_PAD * 4;
    const size_t needPad = recsz + padsz + (size_t)NF * 4;

    const int B = 256;
    if (ws_size >= needFull && nbins <= MAXBINS) {
        float*    fromRec  = (float*)(ws + offFrom);
        float*    toRec    = (float*)(ws + offTo);
        unsigned* pairs    = (unsigned*)(ws + offPair);
        float*    segsum   = (float*)(ws + offSeg);
        unsigned* hist_t   = (unsigned*)(ws + offHist);
        unsigned* binTotal = (unsigned*)(ws + offBT);
        unsigned* binStart = (unsigned*)(ws + offBS);

        pre_node<<<(NF + B - 1) / B, B, 0, stream>>>(from_vec, from_frame, from_pos, W_from, W_attn, 0,  fromRec, NF);
        pre_node<<<(NT + B - 1) / B, B, 0, stream>>>(to_vec, to_frame, to_pos, W_to, W_attn, 12, toRec, NT);
        hist_t_kernel<<<nblk, B, 0, stream>>>(inc, E, nbins, nblk, hist_t);
        scan_rows<<<(nbins * 64 + B - 1) / B, B, 0, stream>>>(hist_t, binTotal, nbins, nblk);
        scan_bins<<<1, 64, 0, stream>>>(binTotal, binStart, nbins);
        edge_score_fused<<<nblk, B, 0, stream>>>(inc, fromRec, toRec, W_attn, hist_t, binStart,
                                                 out, pairs, E, nbins, nblk);
        binsum_kernel<<<nbins, B, 0, stream>>>(pairs, binStart, segsum, NF);
        edge_norm<<<(E + B - 1) / B, B, 0, stream>>>(inc, segsum, out, E);
    } else if (ws_size >= needPad) {
        float* fromRec = (float*)ws;
        float* toRec   = fromRec + (size_t)NF * REC_STRIDE;
        float* segsumP = toRec + (size_t)NT * REC_STRIDE;
        float* segsum  = segsumP + (size_t)NF * NREP * SEG_PAD;
        hipMemsetAsync(segsumP, 0, padsz, stream);
        pre_node<<<(NF + B - 1) / B, B, 0, stream>>>(from_vec, from_frame, from_pos, W_from, W_attn, 0,  fromRec, NF);
        pre_node<<<(NT + B - 1) / B, B, 0, stream>>>(to_vec, to_frame, to_pos, W_to, W_attn, 12, toRec, NT);
        edge_score_pad<<<(E + B - 1) / B, B, 0, stream>>>(inc, fromRec, toRec, W_attn, out, segsumP, E);
        seg_reduce<<<(NF + B - 1) / B, B, 0, stream>>>(segsumP, segsum, NF);
        edge_norm<<<(E + B - 1) / B, B, 0, stream>>>(inc, segsum, out, E);
    }
}

// Round 7
// 122.571 us; speedup vs baseline: 1.0683x; 1.0683x over previous
//
#include <hip/hip_runtime.h>

// Node record layout (stride 16 floats = 64B):
//   [0..8]   Frame[k][j] (row-major)
//   [9..11]  pF[j] = sum_k pos[k]*Frame[k][j]
//   [12..14] pos[0..2]
//   [15]     sA = sum_{h,j} silu(A[h][j]) * Wa[waOff + h*3 + j]
#define REC_STRIDE 16

#define KPB 1024       // keys per bin
#define KPB_SHIFT 10
#define EPB 1024       // edges per chunk (hist + fused score/scatter)
#define MAXBINS 64
#define SLICES 8       // binsum parallelism per bin

#define SEG_PAD 16     // fallback path
#define NREP 2

__device__ __forceinline__ float silu_f(float x)
{
    return x * __builtin_amdgcn_rcpf(1.f + __expf(-x));
}

__global__ void pre_node(const float* __restrict__ vec, const float* __restrict__ frame,
                         const float* __restrict__ pos, const float* __restrict__ W,
                         const float* __restrict__ Wa, int waOff,
                         float* __restrict__ out, int n)
{
    int i = blockIdx.x * blockDim.x + threadIdx.x;
    if (i >= n) return;

    float w[16][3];
#pragma unroll
    for (int d = 0; d < 16; ++d) {
        w[d][0] = W[d * 3 + 0];
        w[d][1] = W[d * 3 + 1];
        w[d][2] = W[d * 3 + 2];
    }
    float vt[3][3] = {{0.f}};  // [k][h]
    const float* vp = vec + (size_t)i * 48;
#pragma unroll
    for (int d = 0; d < 16; ++d) {
        float r0 = vp[d * 3 + 0], r1 = vp[d * 3 + 1], r2 = vp[d * 3 + 2];
#pragma unroll
        for (int h = 0; h < 3; ++h) {
            vt[0][h] += r0 * w[d][h];
            vt[1][h] += r1 * w[d][h];
            vt[2][h] += r2 * w[d][h];
        }
    }
    float F[9];
#pragma unroll
    for (int j = 0; j < 9; ++j) F[j] = frame[(size_t)i * 9 + j];
    float p0 = pos[(size_t)i * 3 + 0];
    float p1 = pos[(size_t)i * 3 + 1];
    float p2 = pos[(size_t)i * 3 + 2];

    float sA = 0.f;
#pragma unroll
    for (int h = 0; h < 3; ++h)
#pragma unroll
        for (int j = 0; j < 3; ++j) {
            float a = vt[0][h] * F[0 + j] + vt[1][h] * F[3 + j] + vt[2][h] * F[6 + j];
            sA += silu_f(a) * Wa[waOff + h * 3 + j];
        }

    float o[16];
#pragma unroll
    for (int j = 0; j < 9; ++j) o[j] = F[j];
#pragma unroll
    for (int j = 0; j < 3; ++j) o[9 + j] = p0 * F[j] + p1 * F[3 + j] + p2 * F[6 + j];
    o[12] = p0; o[13] = p1; o[14] = p2;
    o[15] = sA;

    float4* op = (float4*)(out + (size_t)i * REC_STRIDE);
#pragma unroll
    for (int q = 0; q < 4; ++q) op[q] = ((const float4*)o)[q];
}

// hist, transposed: hist_t[bin * nblk + blk]
__global__ void hist_t_kernel(const int* __restrict__ inc, int E, int nbins, int nblk,
                              unsigned* __restrict__ hist_t)
{
    __shared__ unsigned cnt[MAXBINS];
    if (threadIdx.x < (unsigned)nbins) cnt[threadIdx.x] = 0;
    __syncthreads();
    int base = blockIdx.x * EPB;
#pragma unroll
    for (int it = 0; it < EPB / 256; ++it) {
        int e = base + it * 256 + (int)threadIdx.x;
        if (e < E) {
            int fi = __builtin_nontemporal_load(inc + e);
            atomicAdd(&cnt[fi >> KPB_SHIFT], 1u);
        }
    }
    __syncthreads();
    if (threadIdx.x < (unsigned)nbins)
        hist_t[(size_t)threadIdx.x * nblk + blockIdx.x] = cnt[threadIdx.x];
}

__device__ __forceinline__ unsigned wave_incl_scan(unsigned v, int lane)
{
    int x = (int)v;
#pragma unroll
    for (int d = 1; d < 64; d <<= 1) {
        int t = __shfl_up(x, d, 64);
        if (lane >= d) x += t;
    }
    return (unsigned)x;
}

// one wave per bin: hist_t row -> within-row exclusive prefix; emit row total
__global__ void scan_rows(unsigned* __restrict__ hist_t, unsigned* __restrict__ binTotal,
                          int nbins, int nblk)
{
    int wid = (int)((blockIdx.x * blockDim.x + threadIdx.x) >> 6);
    int lane = (int)(threadIdx.x & 63);
    if (wid >= nbins) return;
    unsigned* row = hist_t + (size_t)wid * nblk;
    unsigned carry = 0;
    for (int c0 = 0; c0 < nblk; c0 += 64) {
        int i = c0 + lane;
        unsigned v = (i < nblk) ? row[i] : 0u;
        unsigned incl = wave_incl_scan(v, lane);
        if (i < nblk) row[i] = (incl - v) + carry;
        carry += (unsigned)__shfl((int)incl, 63, 64);
    }
    if (lane == 0) binTotal[wid] = carry;
}

// single wave: exclusive scan of binTotal -> binStart[0..nbins]
__global__ void scan_bins(const unsigned* __restrict__ binTotal, unsigned* __restrict__ binStart,
                          int nbins)
{
    int lane = (int)(threadIdx.x & 63);
    unsigned carry = 0;
    for (int c0 = 0; c0 < nbins; c0 += 64) {
        int i = c0 + lane;
        unsigned v = (i < nbins) ? binTotal[i] : 0u;
        unsigned incl = wave_incl_scan(v, lane);
        if (i < nbins) binStart[i] = (incl - v) + carry;
        carry += (unsigned)__shfl((int)incl, 63, 64);
    }
    if (lane == 0) binStart[nbins] = carry;
}

// fused: compute ex, write out[e], scatter packed (ex | fi&1023) into bin-grouped pairs
__global__ void edge_score_fused(const int* __restrict__ inc,
                                 const float* __restrict__ fromRec, const float* __restrict__ toRec,
                                 const float* __restrict__ Wa,
                                 const unsigned* __restrict__ hist_t,
                                 const unsigned* __restrict__ binStart,
                                 float* __restrict__ ex_out, unsigned* __restrict__ pairs,
                                 int E, int nbins, int nblk)
{
    __shared__ unsigned cur[MAXBINS];
    if (threadIdx.x < (unsigned)nbins)
        cur[threadIdx.x] = hist_t[(size_t)threadIdx.x * nblk + blockIdx.x] + binStart[threadIdx.x];
    __syncthreads();

    float wa9 = Wa[9], wa10 = Wa[10], wa11 = Wa[11];
    float wa21 = Wa[21], wa22 = Wa[22], wa23 = Wa[23];

    int base = blockIdx.x * EPB;
#pragma unroll
    for (int it = 0; it < EPB / 256; ++it) {
        int e = base + it * 256 + (int)threadIdx.x;
        if (e >= E) break;
        int fi = __builtin_nontemporal_load(inc + e);
        int ti = __builtin_nontemporal_load(inc + E + e);

        float fr[16], tr[16];
        const float4* fp4 = (const float4*)(fromRec + (size_t)fi * REC_STRIDE);
        const float4* tp4 = (const float4*)(toRec + (size_t)ti * REC_STRIDE);
#pragma unroll
        for (int q = 0; q < 4; ++q) ((float4*)fr)[q] = fp4[q];
#pragma unroll
        for (int q = 0; q < 4; ++q) ((float4*)tr)[q] = tp4[q];

        float raw = fr[15] + tr[15];
#pragma unroll
        for (int j = 0; j < 3; ++j) {
            float fd = tr[12] * fr[j] + tr[13] * fr[3 + j] + tr[14] * fr[6 + j] - fr[9 + j];
            float td = fr[12] * tr[j] + fr[13] * tr[3 + j] + fr[14] * tr[6 + j] - tr[9 + j];
            float waf = (j == 0) ? wa9 : (j == 1) ? wa10 : wa11;
            float wat = (j == 0) ? wa21 : (j == 1) ? wa22 : wa23;
            raw += silu_f(fd) * waf + silu_f(td) * wat;
        }

        float ex = __expf(raw);  // shift-invariant softmax, |raw| << 80
        __builtin_nontemporal_store(ex, ex_out + e);

        unsigned slot = atomicAdd(&cur[fi >> KPB_SHIFT], 1u);
        // steal low 10 mantissa bits for the in-bin key (rel err <= 2^-14)
        unsigned w = (__float_as_uint(ex) & ~(unsigned)(KPB - 1)) | (unsigned)(fi & (KPB - 1));
        __builtin_nontemporal_store(w, pairs + slot);
    }
}

// stage 1: per-(bin,slice) partial sums via LDS
__global__ void binsum_part(const unsigned* __restrict__ pairs,
                            const unsigned* __restrict__ binStart,
                            float* __restrict__ partial)
{
    __shared__ float acc[KPB];
    int b = blockIdx.x / SLICES;
    int s = blockIdx.x % SLICES;
#pragma unroll
    for (int t = threadIdx.x; t < KPB; t += 256) acc[t] = 0.f;
    __syncthreads();
    unsigned s0 = binStart[b], s1 = binStart[b + 1];
    unsigned cnt = s1 - s0;
    unsigned chunk = (cnt + SLICES - 1) / SLICES;
    unsigned r0 = s0 + (unsigned)s * chunk;
    unsigned r1 = min(s1, r0 + chunk);
    for (unsigned r = r0 + threadIdx.x; r < r1; r += 256) {
        unsigned w = pairs[r];
        atomicAdd(&acc[w & (KPB - 1)], __uint_as_float(w & ~(unsigned)(KPB - 1)));
    }
    __syncthreads();
    float* dst = partial + (size_t)blockIdx.x * KPB;
#pragma unroll
    for (int t = threadIdx.x; t < KPB; t += 256) dst[t] = acc[t];
}

// stage 2: segsum[k] = sum over slices
__global__ void binsum_reduce(const float* __restrict__ partial, float* __restrict__ segsum, int NF)
{
    int k = blockIdx.x * blockDim.x + threadIdx.x;
    if (k >= NF) return;
    int b = k >> KPB_SHIFT;
    int off = k & (KPB - 1);
    float sum = 0.f;
#pragma unroll
    for (int s = 0; s < SLICES; ++s)
        sum += partial[((size_t)b * SLICES + s) * KPB + off];
    segsum[k] = sum;
}

__global__ void edge_norm(const int* __restrict__ inc, const float* __restrict__ segsum,
                          float* __restrict__ out, int E)
{
    int e = blockIdx.x * blockDim.x + threadIdx.x;
    if (e >= E) return;
    int fi = __builtin_nontemporal_load(inc + e);
    float ex = out[e];
    __builtin_nontemporal_store(ex * __builtin_amdgcn_rcpf(segsum[fi]), out + e);
}

// -------- fallback: padded-replicated atomic edge_score (validated round 5) ----------
__global__ void edge_score_pad(const int* __restrict__ inc,
                               const float* __restrict__ fromRec, const float* __restrict__ toRec,
                               const float* __restrict__ Wa,
                               float* __restrict__ ex_out, float* __restrict__ segsumP, int E)
{
    int e = blockIdx.x * blockDim.x + threadIdx.x;
    if (e >= E) return;
    int fi = __builtin_nontemporal_load(inc + e);
    int ti = __builtin_nontemporal_load(inc + E + e);
    float fr[16], tr[16];
    const float4* fp4 = (const float4*)(fromRec + (size_t)fi * REC_STRIDE);
    const float4* tp4 = (const float4*)(toRec + (size_t)ti * REC_STRIDE);
#pragma unroll
    for (int q = 0; q < 4; ++q) ((float4*)fr)[q] = fp4[q];
#pragma unroll
    for (int q = 0; q < 4; ++q) ((float4*)tr)[q] = tp4[q];
    float raw = fr[15] + tr[15];
#pragma unroll
    for (int j = 0; j < 3; ++j) {
        float fd = tr[12] * fr[j] + tr[13] * fr[3 + j] + tr[14] * fr[6 + j] - fr[9 + j];
        float td = fr[12] * tr[j] + fr[13] * tr[3 + j] + fr[14] * tr[6 + j] - tr[9 + j];
        raw += silu_f(fd) * Wa[9 + j] + silu_f(td) * Wa[21 + j];
    }
    float ex = __expf(raw);
    __builtin_nontemporal_store(ex, ex_out + e);
    size_t slot = ((size_t)fi * NREP + (threadIdx.x & (NREP - 1))) * SEG_PAD;
    atomicAdd(&segsumP[slot], ex);
}

__global__ void seg_reduce(const float* __restrict__ segsumP, float* __restrict__ segsum, int NF)
{
    int k = blockIdx.x * blockDim.x + threadIdx.x;
    if (k >= NF) return;
    float s = 0.f;
#pragma unroll
    for (int r = 0; r < NREP; ++r) s += segsumP[((size_t)k * NREP + r) * SEG_PAD];
    segsum[k] = s;
}

extern "C" void kernel_launch(void* const* d_in, const int* in_sizes, int n_in,
                              void* d_out, int out_size, void* d_ws, size_t ws_size,
                              hipStream_t stream)
{
    const float* from_vec   = (const float*)d_in[0];
    const float* to_vec     = (const float*)d_in[1];
    const float* from_frame = (const float*)d_in[2];
    const float* to_frame   = (const float*)d_in[3];
    const float* from_pos   = (const float*)d_in[4];
    const float* to_pos     = (const float*)d_in[5];
    const float* W_from     = (const float*)d_in[6];
    const float* W_to       = (const float*)d_in[7];
    const float* W_attn     = (const float*)d_in[8];
    const int*   inc        = (const int*)d_in[9];

    const int NF = in_sizes[0] / 48;   // 50000
    const int NT = in_sizes[1] / 48;   // 100000
    const int E  = in_sizes[9] / 2;    // 1600000

    float* out = (float*)d_out;
    unsigned char* ws = (unsigned char*)d_ws;

    const int nbins = (NF + KPB - 1) >> KPB_SHIFT;        // 49
    const int nblk  = (E + EPB - 1) / EPB;                // 1563

    auto align256 = [](size_t x) { return (x + 255) & ~(size_t)255; };

    size_t offFrom = 0;                                                   // also: partial (overlaid)
    size_t offTo   = align256(offFrom + (size_t)NF * REC_STRIDE * 4);
    size_t offPair = align256(offTo   + (size_t)NT * REC_STRIDE * 4);
    size_t offSeg  = align256(offPair + (size_t)E * 4);
    size_t offHist = align256(offSeg  + (size_t)NF * 4);
    size_t offBT   = align256(offHist + (size_t)nbins * nblk * 4);
    size_t offBS   = align256(offBT   + (size_t)nbins * 4);
    size_t needFull = offBS + (size_t)(nbins + 1) * 4;

    const size_t partialSz = (size_t)nbins * SLICES * KPB * 4;            // 1.6MB ≤ fromRec 3.2MB
    const size_t recsz   = ((size_t)NF + NT) * REC_STRIDE * 4;
    const size_t padsz   = (size_t)NF * NREP * SEG_PAD * 4;
    const size_t needPad = recsz + padsz + (size_t)NF * 4;

    const int B = 256;
    if (ws_size >= needFull && nbins <= MAXBINS &&
        partialSz <= (size_t)NF * REC_STRIDE * 4) {
        float*    fromRec  = (float*)(ws + offFrom);
        float*    toRec    = (float*)(ws + offTo);
        unsigned* pairs    = (unsigned*)(ws + offPair);
        float*    segsum   = (float*)(ws + offSeg);
        unsigned* hist_t   = (unsigned*)(ws + offHist);
        unsigned* binTotal = (unsigned*)(ws + offBT);
        unsigned* binStart = (unsigned*)(ws + offBS);
        float*    partial  = (float*)(ws + offFrom);   // overlays fromRec (dead after fused)

        pre_node<<<(NF + B - 1) / B, B, 0, stream>>>(from_vec, from_frame, from_pos, W_from, W_attn, 0,  fromRec, NF);
        pre_node<<<(NT + B - 1) / B, B, 0, stream>>>(to_vec, to_frame, to_pos, W_to, W_attn, 12, toRec, NT);
        hist_t_kernel<<<nblk, B, 0, stream>>>(inc, E, nbins, nblk, hist_t);
        scan_rows<<<(nbins * 64 + B - 1) / B, B, 0, stream>>>(hist_t, binTotal, nbins, nblk);
        scan_bins<<<1, 64, 0, stream>>>(binTotal, binStart, nbins);
        edge_score_fused<<<nblk, B, 0, stream>>>(inc, fromRec, toRec, W_attn, hist_t, binStart,
                                                 out, pairs, E, nbins, nblk);
        binsum_part<<<nbins * SLICES, B, 0, stream>>>(pairs, binStart, partial);
        binsum_reduce<<<(NF + B - 1) / B, B, 0, stream>>>(partial, segsum, NF);
        edge_norm<<<(E + B - 1) / B, B, 0, stream>>>(inc, segsum, out, E);
    } else if (ws_size >= needPad) {
        float* fromRec = (float*)ws;
        float* toRec   = fromRec + (size_t)NF * REC_STRIDE;
        float* segsumP = toRec + (size_t)NT * REC_STRIDE;
        float* segsum  = segsumP + (size_t)NF * NREP * SEG_PAD;
        hipMemsetAsync(segsumP, 0, padsz, stream);
        pre_node<<<(NF + B - 1) / B, B, 0, stream>>>(from_vec, from_frame, from_pos, W_from, W_attn, 0,  fromRec, NF);
        pre_node<<<(NT + B - 1) / B, B, 0, stream>>>(to_vec, to_frame, to_pos, W_to, W_attn, 12, toRec, NT);
        edge_score_pad<<<(E + B - 1) / B, B, 0, stream>>>(inc, fromRec, toRec, W_attn, out, segsumP, E);
        seg_reduce<<<(NF + B - 1) / B, B, 0, stream>>>(segsumP, segsum, NF);
        edge_norm<<<(E + B - 1) / B, B, 0, stream>>>(inc, segsum, out, E);
    }
}